// Round 14
// baseline (255.650 us; speedup 1.0000x reference)
//
#include <hip/hip_runtime.h>
#include <stdint.h>

#define BB 8            // bucket = dst >> 8 (256 dsts per bucket)
#define BSZ 256
#define NBMAX 512       // max buckets per relation (100000>>8 = 391)
#define CAP 6144        // bucket edge capacity (mean ~4096, ~32 sigma margin)

typedef _Float16 half8 __attribute__((ext_vector_type(8)));
typedef float f32x4 __attribute__((ext_vector_type(4)));

// ---------------------------------------------------------------------------
// K1 (frozen, known-good): bin edges into fixed-capacity bucket regions
// P[b*CAP + slot], slots claimed via global atomic cursors.
// Packed: (src<<8 | dst&255).
__global__ void kbin(const int* __restrict__ e1, const int* __restrict__ e2, int E,
                     int* __restrict__ gcur1, int* __restrict__ gcur2,
                     unsigned int* __restrict__ P1, unsigned int* __restrict__ P2,
                     int blocksPerRel) {
    int rel = blockIdx.x >= blocksPerRel;
    int blk = rel ? blockIdx.x - blocksPerRel : blockIdx.x;
    const int* edge = rel ? e2 : e1;
    int* gcur = rel ? gcur2 : gcur1;
    unsigned int* P = rel ? P2 : P1;
    __shared__ int cnt[NBMAX];
    __shared__ int base[NBMAX];
    for (int i = threadIdx.x; i < NBMAX; i += 512) cnt[i] = 0;
    __syncthreads();
    int cbase = blk * 8192;
    int src[16], dst[16], rk[16];
#pragma unroll
    for (int k = 0; k < 16; k++) {
        int i = cbase + k * 512 + threadIdx.x;
        if (i < E) {
            src[k] = edge[i];
            dst[k] = edge[E + i];
            rk[k] = atomicAdd(&cnt[dst[k] >> BB], 1);
        }
    }
    __syncthreads();
    for (int b = threadIdx.x; b < NBMAX; b += 512)
        base[b] = cnt[b] ? atomicAdd(&gcur[b], cnt[b]) : 0;
    __syncthreads();
#pragma unroll
    for (int k = 0; k < 16; k++) {
        int i = cbase + k * 512 + threadIdx.x;
        if (i < E) {
            int b = dst[k] >> BB;
            int slot = base[b] + rk[k];
            if (slot < CAP)
                P[(size_t)b * CAP + slot] =
                    ((unsigned)src[k] << BB) | (unsigned)(dst[k] & (BSZ - 1));
        }
    }
}

// ---------------------------------------------------------------------------
// proj_mfma (NEW, replaces proj_tile's 272 ds_read + 2048 scalar FMA/thread):
// per block (256 thr, 4 waves), C[64x64] = X[64x64] @ [Wy|Ws][64x64] via
// 8x mfma_f32_16x16x32_f16 per wave (wave w = rows 16w..16w+15, 4 col tiles,
// K=64 in 2 chunks). X staged fp32 in LDS (frozen pattern); W^T staged fp16
// [64][72] (b128-readable along k). Fragment layouts (cdna4_isa/m89):
// A: row=l&15, k=(l>>4)*8+j; B: col=l&15, same k; D: col=l&15, row=(l>>4)*4+r.
// C routed through LDS (union with W^T, barrier-protected) for coalesced
// uint4 stores to y (cols 0..31) and s (cols 32..63).
union PjU { _Float16 wT[64][72]; _Float16 cs[64][72]; };

__global__ void __launch_bounds__(256) proj_mfma(
    const float* __restrict__ x1, const float* __restrict__ Wy1, const float* __restrict__ Ws1,
    _Float16* __restrict__ y1, _Float16* __restrict__ s1, int N1, int blocks1,
    const float* __restrict__ x2, const float* __restrict__ Wy2, const float* __restrict__ Ws2,
    _Float16* __restrict__ y2, _Float16* __restrict__ s2, int N2) {
    int rel = blockIdx.x >= blocks1;
    int blk = rel ? blockIdx.x - blocks1 : blockIdx.x;
    const float* x = rel ? x2 : x1;
    const float* Wy = rel ? Wy2 : Wy1;
    const float* Ws = rel ? Ws2 : Ws1;
    _Float16* y = rel ? y2 : y1;
    _Float16* s = rel ? s2 : s1;
    int N = rel ? N2 : N1;

    __shared__ float xs[64][68];
    __shared__ PjU u;

    int tid = threadIdx.x;
    int base = blk << 6;

    // stage X (frozen pattern: coalesced float4, zero-pad past N)
#pragma unroll
    for (int i = 0; i < 4; i++) {
        int idx = i * 256 + tid;
        int row = idx >> 4, c4 = (idx & 15) << 2;
        int node = base + row;
        float4 v = (node < N) ? *(const float4*)(x + ((size_t)node << 6) + c4)
                              : make_float4(0.f, 0.f, 0.f, 0.f);
        *(float4*)&xs[row][c4] = v;
    }
    // stage W^T as fp16: wT[n][k], n<32 -> Wy col n, n>=32 -> Ws col n-32
#pragma unroll
    for (int i = 0; i < 16; i++) {
        int idx = i * 256 + tid;          // 0..4095
        int k = idx >> 6, n = idx & 63;
        float v = (n < 32) ? Wy[k * 32 + n] : Ws[k * 32 + (n - 32)];
        u.wT[n][k] = (_Float16)v;
    }
    __syncthreads();

    int l = tid & 63;
    int w = tid >> 6;            // wave id = C row block
    int fr = l & 15;             // fragment row (A) / col (B,D)
    int kg = l >> 4;             // k-group (0..3)

    // A fragments (2 K-chunks) from xs, cvt fp32->fp16
    half8 afrag[2];
#pragma unroll
    for (int c = 0; c < 2; c++) {
        const float* src = &xs[(w << 4) + fr][(c << 5) + (kg << 3)];
        float4 p0 = *(const float4*)(src);
        float4 p1 = *(const float4*)(src + 4);
        afrag[c][0] = (_Float16)p0.x; afrag[c][1] = (_Float16)p0.y;
        afrag[c][2] = (_Float16)p0.z; afrag[c][3] = (_Float16)p0.w;
        afrag[c][4] = (_Float16)p1.x; afrag[c][5] = (_Float16)p1.y;
        afrag[c][6] = (_Float16)p1.z; afrag[c][7] = (_Float16)p1.w;
    }

    // B fragments (4 col tiles x 2 K-chunks): b128 reads along k from wT
    half8 bfrag[4][2];
#pragma unroll
    for (int t = 0; t < 4; t++)
#pragma unroll
        for (int c = 0; c < 2; c++)
            bfrag[t][c] = *(const half8*)&u.wT[(t << 4) + fr][(c << 5) + (kg << 3)];

    f32x4 acc0 = {0,0,0,0}, acc1 = {0,0,0,0}, acc2 = {0,0,0,0}, acc3 = {0,0,0,0};
    acc0 = __builtin_amdgcn_mfma_f32_16x16x32_f16(afrag[0], bfrag[0][0], acc0, 0, 0, 0);
    acc0 = __builtin_amdgcn_mfma_f32_16x16x32_f16(afrag[1], bfrag[0][1], acc0, 0, 0, 0);
    acc1 = __builtin_amdgcn_mfma_f32_16x16x32_f16(afrag[0], bfrag[1][0], acc1, 0, 0, 0);
    acc1 = __builtin_amdgcn_mfma_f32_16x16x32_f16(afrag[1], bfrag[1][1], acc1, 0, 0, 0);
    acc2 = __builtin_amdgcn_mfma_f32_16x16x32_f16(afrag[0], bfrag[2][0], acc2, 0, 0, 0);
    acc2 = __builtin_amdgcn_mfma_f32_16x16x32_f16(afrag[1], bfrag[2][1], acc2, 0, 0, 0);
    acc3 = __builtin_amdgcn_mfma_f32_16x16x32_f16(afrag[0], bfrag[3][0], acc3, 0, 0, 0);
    acc3 = __builtin_amdgcn_mfma_f32_16x16x32_f16(afrag[1], bfrag[3][1], acc3, 0, 0, 0);

    __syncthreads();   // all wT reads complete block-wide; cs may now overwrite

    // D layout: row = (l>>4)*4 + r, col = l&15 (m89-verified, dtype-indep)
    int crow = (w << 4) + (kg << 2);
#pragma unroll
    for (int r = 0; r < 4; r++) {
        u.cs[crow + r][fr]      = (_Float16)acc0[r];
        u.cs[crow + r][16 + fr] = (_Float16)acc1[r];
        u.cs[crow + r][32 + fr] = (_Float16)acc2[r];
        u.cs[crow + r][48 + fr] = (_Float16)acc3[r];
    }
    __syncthreads();

    // coalesced write-out: 4 threads/node, 16 f16 each (2x uint4)
    int node = tid & 63;
    int grp = tid >> 6;          // 0,1 -> y cols 0/16; 2,3 -> s cols 0/16
    int ng = base + node;
    if (ng < N) {
        uint4 v0 = *(const uint4*)&u.cs[node][grp << 4];
        uint4 v1 = *(const uint4*)&u.cs[node][(grp << 4) + 8];
        _Float16* dst = (grp < 2) ? y : s;
        int col = (grp & 1) << 4;
        *(uint4*)(dst + ((size_t)ng << 5) + col) = v0;
        *(uint4*)(dst + ((size_t)ng << 5) + col + 8) = v1;
    }
}

// ---------------------------------------------------------------------------
// FUSED sort+pull — R8-proven single-pass pull (R13's 2-node interleave
// reverted: null). In-kernel head constants + cbias (kinit deleted).
// XCD map: rel0 -> XCDs 0-3, rel1 -> 4-7.
__global__ void __launch_bounds__(512, 1) sortpull(
    const unsigned int* __restrict__ Pp, const int* __restrict__ gcur_p,
    const _Float16* __restrict__ y_c, const _Float16* __restrict__ sp,
    const float* __restrict__ b_p, float* __restrict__ u_p, int NP, int nbP,
    const unsigned int* __restrict__ Pc, const int* __restrict__ gcur_c,
    const _Float16* __restrict__ y_p, const _Float16* __restrict__ sc_,
    const float* __restrict__ b_c, float* __restrict__ t_c, int NC, int nbC,
    const float* __restrict__ W2l, const float* __restrict__ W2r,
    const float* __restrict__ b2, const float* __restrict__ Wlin,
    const float* __restrict__ blin, float* __restrict__ cbout,
    int* __restrict__ ss_p, int* __restrict__ ro_p, int* __restrict__ dg_p) {
    int x = blockIdx.x;
    int xcd = x & 7, k = x >> 3;
    int rel = xcd >= 4;
    int b = k * 4 + (xcd & 3);
    int nb = rel ? nbC : nbP;
    if (b >= nb) return;

    const unsigned int* P = (rel ? Pc : Pp) + (size_t)b * CAP;
    int m = min((rel ? gcur_c : gcur_p)[b], CAP);
    const _Float16* y = rel ? y_p : y_c;
    const _Float16* sf = rel ? sc_ : sp;
    const float* bv = rel ? b_c : b_p;
    float* tgt = rel ? t_c : u_p;
    int N = rel ? NC : NP;

    __shared__ int cnt[BSZ];
    __shared__ int excl[BSZ];
    __shared__ int cur[BSZ];
    __shared__ int wsum[4];
    __shared__ float hc[64];
    __shared__ int stage[CAP];

    int d0 = b << BB;
    int nd = min(BSZ, N - d0);
    int tid = threadIdx.x;

    // head constants: v2l = W2l@Wlin (hc[0..31]), v2r = W2r@Wlin (hc[32..63])
    if (tid < 64) {
        const float* W = (tid < 32) ? W2l : W2r;
        int kk = tid & 31;
        float acc = 0.0f;
#pragma unroll
        for (int j = 0; j < 32; j++) acc += W[kk * 32 + j] * Wlin[j];
        hc[tid] = acc;
    }
    if (blockIdx.x == 0 && tid == 64) {
        float acc = blin[0];
#pragma unroll
        for (int j = 0; j < 32; j++) acc += b2[j] * Wlin[j];
        *cbout = acc;   // cbias for pull_l2
    }

    // ---- phase 1: counting sort (frozen) ----
    if (tid < BSZ) cnt[tid] = 0;
    __syncthreads();
    for (int i = tid; i < m; i += 512) atomicAdd(&cnt[P[i] & (BSZ - 1)], 1);
    __syncthreads();
    int lane = tid & 63, wid = tid >> 6;
    if (tid < BSZ) {
        int v = cnt[tid], sc = v;
#pragma unroll
        for (int off = 1; off < 64; off <<= 1) {
            int t = __shfl_up(sc, off, 64);
            if (lane >= off) sc += t;
        }
        if (lane == 63) wsum[wid] = sc;
        int vkeep = v, sckeep = sc;
        __syncthreads();
        int woff = 0;
        for (int w = 0; w < wid; w++) woff += wsum[w];
        int e = woff + sckeep - vkeep;
        excl[tid] = e;
        cur[tid] = e;
    } else {
        __syncthreads();
    }
    __syncthreads();
    for (int i = tid; i < m; i += 512) {
        unsigned int p = P[i];
        int slot = atomicAdd(&cur[p & (BSZ - 1)], 1);
        stage[slot] = (int)(p >> BB);
    }
    __syncthreads();

    // rel0: persist CSR for pull_l2 (ss/ro/dg of product nodes)
    if (!rel) {
        for (int i = tid; i < m; i += 512) ss_p[(size_t)b * CAP + i] = stage[i];
        if (tid < nd) {
            ro_p[d0 + tid] = b * CAP + excl[tid];
            dg_p[d0 + tid] = cnt[tid];
        }
    }

    // ---- phase 2: pull (R8-proven loop; srcs from LDS stage) ----
    int l = tid & 31;
    int g = tid >> 5;                 // 16 node-groups of 32 lanes
    int el = l >> 2, sub = l & 3;

    const float* v2 = rel ? hc : hc + 32;  // t_c: v2l, u_p: v2r
    float4 b0 = *(const float4*)(bv + (sub << 3));
    float4 b1 = *(const float4*)(bv + (sub << 3) + 4);
    float4 w0 = *(const float4*)(v2 + (sub << 3));
    float4 w1 = *(const float4*)(v2 + (sub << 3) + 4);
    float bb[8] = {b0.x, b0.y, b0.z, b0.w, b1.x, b1.y, b1.z, b1.w};
    float ww[8] = {w0.x, w0.y, w0.z, w0.w, w1.x, w1.y, w1.z, w1.w};

    union U { uint4 v; half8 h; };
    for (int nl = g; nl < nd; nl += 16) {
        int node = d0 + nl;
        int start = excl[nl], deg = cnt[nl];

        half8 acc8 = (half8)(_Float16)0;
        for (int base = 0; base < deg; base += 16) {
            int j0 = base + el, j1 = base + 8 + el;
            bool v0 = j0 < deg, v1 = j1 < deg;
            int s0 = v0 ? stage[start + j0] : 0;
            int s1 = v1 ? stage[start + j1] : 0;
            U q0, q1;
            if (v0) q0.v = *(const uint4*)(y + ((size_t)s0 << 5) + (sub << 3));
            if (v1) q1.v = *(const uint4*)(y + ((size_t)s1 << 5) + (sub << 3));
            if (v0) acc8 += q0.h;
            if (v1) acc8 += q1.h;
        }
#pragma unroll
        for (int off = 4; off <= 16; off <<= 1) {
            U t, r;
            t.h = acc8;
            r.v.x = __shfl_xor(t.v.x, off, 32);
            r.v.y = __shfl_xor(t.v.y, off, 32);
            r.v.z = __shfl_xor(t.v.z, off, 32);
            r.v.w = __shfl_xor(t.v.w, off, 32);
            acc8 += r.h;
        }

        float invd = 1.0f / fmaxf((float)deg, 1.0f);
        union { uint4 v; _Float16 h[8]; } us;
        us.v = *(const uint4*)(sf + ((size_t)node << 5) + (sub << 3));
        float p = 0.0f;
#pragma unroll
        for (int j = 0; j < 8; j++) {
            float r = bb[j] + (float)us.h[j] + (float)acc8[j] * invd;
            p += fmaxf(r, 0.0f) * ww[j];
        }
        p += __shfl_xor(p, 1, 32);
        p += __shfl_xor(p, 2, 32);
        if (l == 0) tgt[node] = p;
    }
}

// ---------------------------------------------------------------------------
// layer-2 scalar pull (frozen): logit = mean t_c[src] + u_p[node] + cbias
__global__ void pull_l2_scalar(const int* __restrict__ ro, const int* __restrict__ dg,
                               const int* __restrict__ ss,
                               const float* __restrict__ t_c, const float* __restrict__ u_p,
                               const float* __restrict__ hconst,
                               float* __restrict__ out, int N) {
    int gid = blockIdx.x * blockDim.x + threadIdx.x;
    int node = gid >> 2, ln = gid & 3;
    if (node >= N) return;
    int s = ro[node], deg = dg[node], e = s + deg;
    float acc = 0.0f;
    for (int j = s + ln; j < e; j += 4) acc += t_c[ss[j]];
    acc += __shfl_xor(acc, 1, 4);
    acc += __shfl_xor(acc, 2, 4);
    if (ln == 0) {
        float logit = acc / fmaxf((float)deg, 1.0f) + u_p[node] + hconst[64];
        out[node] = 1.0f / (1.0f + expf(-logit));
    }
}

// ---------------------------------------------------------------------------
extern "C" void kernel_launch(void* const* d_in, const int* in_sizes, int n_in,
                              void* d_out, int out_size, void* d_ws, size_t ws_size,
                              hipStream_t stream) {
    const float* xc    = (const float*)d_in[0];
    const float* xp    = (const float*)d_in[1];
    const int*   e_c2p = (const int*)d_in[2];   // src=cust, dst=prod
    const int*   e_p2c = (const int*)d_in[3];   // src=prod, dst=cust
    const float* W1l_r1 = (const float*)d_in[4];
    const float* b1_r1  = (const float*)d_in[5];
    const float* W1r_r1 = (const float*)d_in[6];
    const float* W1l_r2 = (const float*)d_in[7];
    const float* b1_r2  = (const float*)d_in[8];
    const float* W1r_r2 = (const float*)d_in[9];
    const float* W2l_r1 = (const float*)d_in[10];
    const float* b2_r1  = (const float*)d_in[11];
    const float* W2r_r1 = (const float*)d_in[12];
    const float* Wlin  = (const float*)d_in[16];
    const float* blin  = (const float*)d_in[17];
    float* out = (float*)d_out;

    const int NC = in_sizes[0] / 64;
    const int NP = in_sizes[1] / 64;
    const int E  = in_sizes[2] / 2;
    const int nbP = (NP + BSZ - 1) >> BB;
    const int nbC = (NC + BSZ - 1) >> BB;

    // ---- workspace layout ----
    char* w = (char*)d_ws;
    int* gcur_p = (int*)w;  w += NBMAX * 4;     // zeroed together (memset)
    int* gcur_c = (int*)w;  w += NBMAX * 4;
    float* hconst = (float*)w; w += 68 * 4;     // only [64] (cbias) used
    w = (char*)(((uintptr_t)w + 255) & ~(uintptr_t)255);
    unsigned int* P_p = (unsigned int*)w;  w += (size_t)nbP * CAP * 4;
    unsigned int* P_c = (unsigned int*)w;  w += (size_t)nbC * CAP * 4;
    int* ss_p = (int*)w;    w += (size_t)nbP * CAP * 4;
    int* ro_p = (int*)w;    w += (size_t)NP * 4;
    int* dg_p = (int*)w;    w += (size_t)NP * 4;
    w = (char*)(((uintptr_t)w + 255) & ~(uintptr_t)255);
    _Float16* y_c = (_Float16*)w; w += (size_t)NC * 32 * 2;
    _Float16* y_p = (_Float16*)w; w += (size_t)NP * 32 * 2;
    _Float16* s_p = (_Float16*)w; w += (size_t)NP * 32 * 2;  // xp @ W1r_r1
    _Float16* s_c = (_Float16*)w; w += (size_t)NC * 32 * 2;  // xc @ W1r_r2
    w = (char*)(((uintptr_t)w + 255) & ~(uintptr_t)255);
    float* t_c = (float*)w; w += (size_t)NC * 4;
    float* u_p = (float*)w; w += (size_t)NP * 4;

    const int bprB = (E + 8191) / 8192;

    // 1. zero bucket cursors (no kernel launch)
    hipMemsetAsync(gcur_p, 0, 2 * NBMAX * 4, stream);

    // 2. bucket binning (frozen)
    kbin<<<2 * bprB, 512, 0, stream>>>(e_c2p, e_p2c, E, gcur_p, gcur_c, P_p, P_c, bprB);

    // 3. MFMA fused projections (y fp16 + s fp16; both node types)
    const int tblocksC = (NC + 63) / 64;
    const int tblocksP = (NP + 63) / 64;
    proj_mfma<<<tblocksC + tblocksP, 256, 0, stream>>>(
        xc, W1l_r1, W1r_r2, y_c, s_c, NC, tblocksC,
        xp, W1l_r2, W1r_r1, y_p, s_p, NP);

    // 4. fused per-bucket sort + layer-1 pull (R8-proven)
    const int nbMax = (nbP > nbC) ? nbP : nbC;
    const int spBlocks = 8 * ((nbMax + 3) / 4);
    sortpull<<<spBlocks, 512, 0, stream>>>(
        P_p, gcur_p, y_c, s_p, b1_r1, u_p, NP, nbP,
        P_c, gcur_c, y_p, s_c, b1_r2, t_c, NC, nbC,
        W2l_r1, W2r_r1, b2_r1, Wlin, blin, hconst + 64,
        ss_p, ro_p, dg_p);

    // 5. layer-2 scalar pull + sigmoid (4B gathers from 400KB table)
    pull_l2_scalar<<<(NP * 4 + 255) / 256, 256, 0, stream>>>(
        ro_p, dg_p, ss_p, t_c, u_p, hconst, out, NP);
}

// Round 15
// 235.049 us; speedup vs baseline: 1.0876x; 1.0876x over previous
//
#include <hip/hip_runtime.h>
#include <stdint.h>

#define BB 8            // bucket = dst >> 8 (256 dsts per bucket)
#define BSZ 256
#define NBMAX 512       // max buckets per relation (100000>>8 = 391)
#define CAP 6144        // bucket edge capacity (mean ~4096, ~32 sigma margin)

typedef _Float16 half8 __attribute__((ext_vector_type(8)));
typedef float f32x4 __attribute__((ext_vector_type(4)));

// ---------------------------------------------------------------------------
// init (restored from R8): block 0 zeroes bucket cursors; block 1 computes
// head constants (v2l = W2l@Wlin, v2r = W2r@Wlin, cbias = b2.Wlin + blin).
__global__ void kinit(int4* __restrict__ gcur, int n4,
                      const float* __restrict__ W2l, const float* __restrict__ W2r,
                      const float* __restrict__ b2, const float* __restrict__ Wlin,
                      const float* __restrict__ blin, float* __restrict__ hconst) {
    if (blockIdx.x == 0) {
        for (int i = threadIdx.x; i < n4; i += 256) gcur[i] = make_int4(0, 0, 0, 0);
    } else {
        int t = threadIdx.x;
        if (t < 64) {
            const float* W = (t < 32) ? W2l : W2r;
            int k = t & 31;
            float acc = 0.0f;
#pragma unroll
            for (int j = 0; j < 32; j++) acc += W[k * 32 + j] * Wlin[j];
            hconst[t] = acc;
        }
        if (t == 64) {
            float acc = blin[0];
#pragma unroll
            for (int j = 0; j < 32; j++) acc += b2[j] * Wlin[j];
            hconst[64] = acc;
        }
    }
}

// ---------------------------------------------------------------------------
// K1 (frozen, known-good): bin edges into fixed-capacity bucket regions
// P[b*CAP + slot], slots claimed via global atomic cursors.
// Packed: (src<<8 | dst&255).
__global__ void kbin(const int* __restrict__ e1, const int* __restrict__ e2, int E,
                     int* __restrict__ gcur1, int* __restrict__ gcur2,
                     unsigned int* __restrict__ P1, unsigned int* __restrict__ P2,
                     int blocksPerRel) {
    int rel = blockIdx.x >= blocksPerRel;
    int blk = rel ? blockIdx.x - blocksPerRel : blockIdx.x;
    const int* edge = rel ? e2 : e1;
    int* gcur = rel ? gcur2 : gcur1;
    unsigned int* P = rel ? P2 : P1;
    __shared__ int cnt[NBMAX];
    __shared__ int base[NBMAX];
    for (int i = threadIdx.x; i < NBMAX; i += 512) cnt[i] = 0;
    __syncthreads();
    int cbase = blk * 8192;
    int src[16], dst[16], rk[16];
#pragma unroll
    for (int k = 0; k < 16; k++) {
        int i = cbase + k * 512 + threadIdx.x;
        if (i < E) {
            src[k] = edge[i];
            dst[k] = edge[E + i];
            rk[k] = atomicAdd(&cnt[dst[k] >> BB], 1);
        }
    }
    __syncthreads();
    for (int b = threadIdx.x; b < NBMAX; b += 512)
        base[b] = cnt[b] ? atomicAdd(&gcur[b], cnt[b]) : 0;
    __syncthreads();
#pragma unroll
    for (int k = 0; k < 16; k++) {
        int i = cbase + k * 512 + threadIdx.x;
        if (i < E) {
            int b = dst[k] >> BB;
            int slot = base[b] + rk[k];
            if (slot < CAP)
                P[(size_t)b * CAP + slot] =
                    ((unsigned)src[k] << BB) | (unsigned)(dst[k] & (BSZ - 1));
        }
    }
}

// ---------------------------------------------------------------------------
// proj_mfma (refcheck-proven in R14): per block (256 thr, 4 waves),
// C[64x64] = X[64x64] @ [Wy|Ws][64x64] via 8x mfma_f32_16x16x32_f16/wave.
// X staged fp32 in LDS; W^T staged fp16 [64][72]. Fragment layouts per
// cdna4_isa/m89. C routed through LDS (union with W^T) for coalesced stores.
union PjU { _Float16 wT[64][72]; _Float16 cs[64][72]; };

__global__ void __launch_bounds__(256) proj_mfma(
    const float* __restrict__ x1, const float* __restrict__ Wy1, const float* __restrict__ Ws1,
    _Float16* __restrict__ y1, _Float16* __restrict__ s1, int N1, int blocks1,
    const float* __restrict__ x2, const float* __restrict__ Wy2, const float* __restrict__ Ws2,
    _Float16* __restrict__ y2, _Float16* __restrict__ s2, int N2) {
    int rel = blockIdx.x >= blocks1;
    int blk = rel ? blockIdx.x - blocks1 : blockIdx.x;
    const float* x = rel ? x2 : x1;
    const float* Wy = rel ? Wy2 : Wy1;
    const float* Ws = rel ? Ws2 : Ws1;
    _Float16* y = rel ? y2 : y1;
    _Float16* s = rel ? s2 : s1;
    int N = rel ? N2 : N1;

    __shared__ float xs[64][68];
    __shared__ PjU u;

    int tid = threadIdx.x;
    int base = blk << 6;

#pragma unroll
    for (int i = 0; i < 4; i++) {
        int idx = i * 256 + tid;
        int row = idx >> 4, c4 = (idx & 15) << 2;
        int node = base + row;
        float4 v = (node < N) ? *(const float4*)(x + ((size_t)node << 6) + c4)
                              : make_float4(0.f, 0.f, 0.f, 0.f);
        *(float4*)&xs[row][c4] = v;
    }
#pragma unroll
    for (int i = 0; i < 16; i++) {
        int idx = i * 256 + tid;          // 0..4095
        int k = idx >> 6, n = idx & 63;
        float v = (n < 32) ? Wy[k * 32 + n] : Ws[k * 32 + (n - 32)];
        u.wT[n][k] = (_Float16)v;
    }
    __syncthreads();

    int l = tid & 63;
    int w = tid >> 6;            // wave id = C row block
    int fr = l & 15;             // fragment row (A) / col (B,D)
    int kg = l >> 4;             // k-group (0..3)

    half8 afrag[2];
#pragma unroll
    for (int c = 0; c < 2; c++) {
        const float* src = &xs[(w << 4) + fr][(c << 5) + (kg << 3)];
        float4 p0 = *(const float4*)(src);
        float4 p1 = *(const float4*)(src + 4);
        afrag[c][0] = (_Float16)p0.x; afrag[c][1] = (_Float16)p0.y;
        afrag[c][2] = (_Float16)p0.z; afrag[c][3] = (_Float16)p0.w;
        afrag[c][4] = (_Float16)p1.x; afrag[c][5] = (_Float16)p1.y;
        afrag[c][6] = (_Float16)p1.z; afrag[c][7] = (_Float16)p1.w;
    }

    half8 bfrag[4][2];
#pragma unroll
    for (int t = 0; t < 4; t++)
#pragma unroll
        for (int c = 0; c < 2; c++)
            bfrag[t][c] = *(const half8*)&u.wT[(t << 4) + fr][(c << 5) + (kg << 3)];

    f32x4 acc0 = {0,0,0,0}, acc1 = {0,0,0,0}, acc2 = {0,0,0,0}, acc3 = {0,0,0,0};
    acc0 = __builtin_amdgcn_mfma_f32_16x16x32_f16(afrag[0], bfrag[0][0], acc0, 0, 0, 0);
    acc0 = __builtin_amdgcn_mfma_f32_16x16x32_f16(afrag[1], bfrag[0][1], acc0, 0, 0, 0);
    acc1 = __builtin_amdgcn_mfma_f32_16x16x32_f16(afrag[0], bfrag[1][0], acc1, 0, 0, 0);
    acc1 = __builtin_amdgcn_mfma_f32_16x16x32_f16(afrag[1], bfrag[1][1], acc1, 0, 0, 0);
    acc2 = __builtin_amdgcn_mfma_f32_16x16x32_f16(afrag[0], bfrag[2][0], acc2, 0, 0, 0);
    acc2 = __builtin_amdgcn_mfma_f32_16x16x32_f16(afrag[1], bfrag[2][1], acc2, 0, 0, 0);
    acc3 = __builtin_amdgcn_mfma_f32_16x16x32_f16(afrag[0], bfrag[3][0], acc3, 0, 0, 0);
    acc3 = __builtin_amdgcn_mfma_f32_16x16x32_f16(afrag[1], bfrag[3][1], acc3, 0, 0, 0);

    __syncthreads();   // all wT reads complete block-wide; cs may now overwrite

    int crow = (w << 4) + (kg << 2);
#pragma unroll
    for (int r = 0; r < 4; r++) {
        u.cs[crow + r][fr]      = (_Float16)acc0[r];
        u.cs[crow + r][16 + fr] = (_Float16)acc1[r];
        u.cs[crow + r][32 + fr] = (_Float16)acc2[r];
        u.cs[crow + r][48 + fr] = (_Float16)acc3[r];
    }
    __syncthreads();

    int node = tid & 63;
    int grp = tid >> 6;          // 0,1 -> y cols 0/16; 2,3 -> s cols 0/16
    int ng = base + node;
    if (ng < N) {
        uint4 v0 = *(const uint4*)&u.cs[node][grp << 4];
        uint4 v1 = *(const uint4*)&u.cs[node][(grp << 4) + 8];
        _Float16* dst = (grp < 2) ? y : s;
        int col = (grp & 1) << 4;
        *(uint4*)(dst + ((size_t)ng << 5) + col) = v0;
        *(uint4*)(dst + ((size_t)ng << 5) + col + 8) = v1;
    }
}

// ---------------------------------------------------------------------------
// FUSED sort+pull — BYTE-EXACT R8 version (63.2us): reads precomputed
// hconst (kinit restored; the R9-era in-kernel hc correlates with the
// 65-75us sortpull inflation). XCD map: rel0 -> XCDs 0-3, rel1 -> 4-7.
__global__ void __launch_bounds__(512, 1) sortpull(
    const unsigned int* __restrict__ Pp, const int* __restrict__ gcur_p,
    const _Float16* __restrict__ y_c, const _Float16* __restrict__ sp,
    const float* __restrict__ b_p, float* __restrict__ u_p, int NP, int nbP,
    const unsigned int* __restrict__ Pc, const int* __restrict__ gcur_c,
    const _Float16* __restrict__ y_p, const _Float16* __restrict__ sc_,
    const float* __restrict__ b_c, float* __restrict__ t_c, int NC, int nbC,
    const float* __restrict__ hconst,
    int* __restrict__ ss_p, int* __restrict__ ro_p, int* __restrict__ dg_p) {
    int x = blockIdx.x;
    int xcd = x & 7, k = x >> 3;
    int rel = xcd >= 4;
    int b = k * 4 + (xcd & 3);
    int nb = rel ? nbC : nbP;
    if (b >= nb) return;

    const unsigned int* P = (rel ? Pc : Pp) + (size_t)b * CAP;
    int m = min((rel ? gcur_c : gcur_p)[b], CAP);
    const _Float16* y = rel ? y_p : y_c;
    const _Float16* sf = rel ? sc_ : sp;
    const float* bv = rel ? b_c : b_p;
    const float* v2 = rel ? hconst : hconst + 32;  // t_c: v2l, u_p: v2r
    float* tgt = rel ? t_c : u_p;
    int N = rel ? NC : NP;

    __shared__ int cnt[BSZ];
    __shared__ int excl[BSZ];
    __shared__ int cur[BSZ];
    __shared__ int wsum[4];
    __shared__ int stage[CAP];

    int d0 = b << BB;
    int nd = min(BSZ, N - d0);
    int tid = threadIdx.x;

    // ---- phase 1: counting sort (frozen) ----
    if (tid < BSZ) cnt[tid] = 0;
    __syncthreads();
    for (int i = tid; i < m; i += 512) atomicAdd(&cnt[P[i] & (BSZ - 1)], 1);
    __syncthreads();
    int lane = tid & 63, wid = tid >> 6;
    if (tid < BSZ) {
        int v = cnt[tid], sc = v;
#pragma unroll
        for (int off = 1; off < 64; off <<= 1) {
            int t = __shfl_up(sc, off, 64);
            if (lane >= off) sc += t;
        }
        if (lane == 63) wsum[wid] = sc;
        int vkeep = v, sckeep = sc;
        __syncthreads();
        int woff = 0;
        for (int w = 0; w < wid; w++) woff += wsum[w];
        int e = woff + sckeep - vkeep;
        excl[tid] = e;
        cur[tid] = e;
    } else {
        __syncthreads();
    }
    __syncthreads();
    for (int i = tid; i < m; i += 512) {
        unsigned int p = P[i];
        int slot = atomicAdd(&cur[p & (BSZ - 1)], 1);
        stage[slot] = (int)(p >> BB);
    }
    __syncthreads();

    // rel0: persist CSR for pull_l2 (ss/ro/dg of product nodes)
    if (!rel) {
        for (int i = tid; i < m; i += 512) ss_p[(size_t)b * CAP + i] = stage[i];
        if (tid < nd) {
            ro_p[d0 + tid] = b * CAP + excl[tid];
            dg_p[d0 + tid] = cnt[tid];
        }
    }

    // ---- phase 2: pull (R8-proven loop; srcs from LDS stage) ----
    int l = tid & 31;
    int g = tid >> 5;                 // 16 node-groups of 32 lanes
    int el = l >> 2, sub = l & 3;

    float4 b0 = *(const float4*)(bv + (sub << 3));
    float4 b1 = *(const float4*)(bv + (sub << 3) + 4);
    float4 w0 = *(const float4*)(v2 + (sub << 3));
    float4 w1 = *(const float4*)(v2 + (sub << 3) + 4);
    float bb[8] = {b0.x, b0.y, b0.z, b0.w, b1.x, b1.y, b1.z, b1.w};
    float ww[8] = {w0.x, w0.y, w0.z, w0.w, w1.x, w1.y, w1.z, w1.w};

    union U { uint4 v; half8 h; };
    for (int nl = g; nl < nd; nl += 16) {
        int node = d0 + nl;
        int start = excl[nl], deg = cnt[nl];

        half8 acc8 = (half8)(_Float16)0;
        for (int base = 0; base < deg; base += 16) {
            int j0 = base + el, j1 = base + 8 + el;
            bool v0 = j0 < deg, v1 = j1 < deg;
            int s0 = v0 ? stage[start + j0] : 0;
            int s1 = v1 ? stage[start + j1] : 0;
            U q0, q1;
            if (v0) q0.v = *(const uint4*)(y + ((size_t)s0 << 5) + (sub << 3));
            if (v1) q1.v = *(const uint4*)(y + ((size_t)s1 << 5) + (sub << 3));
            if (v0) acc8 += q0.h;
            if (v1) acc8 += q1.h;
        }
#pragma unroll
        for (int off = 4; off <= 16; off <<= 1) {
            U t, r;
            t.h = acc8;
            r.v.x = __shfl_xor(t.v.x, off, 32);
            r.v.y = __shfl_xor(t.v.y, off, 32);
            r.v.z = __shfl_xor(t.v.z, off, 32);
            r.v.w = __shfl_xor(t.v.w, off, 32);
            acc8 += r.h;
        }

        float invd = 1.0f / fmaxf((float)deg, 1.0f);
        union { uint4 v; _Float16 h[8]; } us;
        us.v = *(const uint4*)(sf + ((size_t)node << 5) + (sub << 3));
        float p = 0.0f;
#pragma unroll
        for (int j = 0; j < 8; j++) {
            float r = bb[j] + (float)us.h[j] + (float)acc8[j] * invd;
            p += fmaxf(r, 0.0f) * ww[j];
        }
        p += __shfl_xor(p, 1, 32);
        p += __shfl_xor(p, 2, 32);
        if (l == 0) tgt[node] = p;
    }
}

// ---------------------------------------------------------------------------
// layer-2 scalar pull (frozen): logit = mean t_c[src] + u_p[node] + cbias
__global__ void pull_l2_scalar(const int* __restrict__ ro, const int* __restrict__ dg,
                               const int* __restrict__ ss,
                               const float* __restrict__ t_c, const float* __restrict__ u_p,
                               const float* __restrict__ hconst,
                               float* __restrict__ out, int N) {
    int gid = blockIdx.x * blockDim.x + threadIdx.x;
    int node = gid >> 2, ln = gid & 3;
    if (node >= N) return;
    int s = ro[node], deg = dg[node], e = s + deg;
    float acc = 0.0f;
    for (int j = s + ln; j < e; j += 4) acc += t_c[ss[j]];
    acc += __shfl_xor(acc, 1, 4);
    acc += __shfl_xor(acc, 2, 4);
    if (ln == 0) {
        float logit = acc / fmaxf((float)deg, 1.0f) + u_p[node] + hconst[64];
        out[node] = 1.0f / (1.0f + expf(-logit));
    }
}

// ---------------------------------------------------------------------------
extern "C" void kernel_launch(void* const* d_in, const int* in_sizes, int n_in,
                              void* d_out, int out_size, void* d_ws, size_t ws_size,
                              hipStream_t stream) {
    const float* xc    = (const float*)d_in[0];
    const float* xp    = (const float*)d_in[1];
    const int*   e_c2p = (const int*)d_in[2];   // src=cust, dst=prod
    const int*   e_p2c = (const int*)d_in[3];   // src=prod, dst=cust
    const float* W1l_r1 = (const float*)d_in[4];
    const float* b1_r1  = (const float*)d_in[5];
    const float* W1r_r1 = (const float*)d_in[6];
    const float* W1l_r2 = (const float*)d_in[7];
    const float* b1_r2  = (const float*)d_in[8];
    const float* W1r_r2 = (const float*)d_in[9];
    const float* W2l_r1 = (const float*)d_in[10];
    const float* b2_r1  = (const float*)d_in[11];
    const float* W2r_r1 = (const float*)d_in[12];
    const float* Wlin  = (const float*)d_in[16];
    const float* blin  = (const float*)d_in[17];
    float* out = (float*)d_out;

    const int NC = in_sizes[0] / 64;
    const int NP = in_sizes[1] / 64;
    const int E  = in_sizes[2] / 2;
    const int nbP = (NP + BSZ - 1) >> BB;
    const int nbC = (NC + BSZ - 1) >> BB;

    // ---- workspace layout ----
    char* w = (char*)d_ws;
    int* gcur_p = (int*)w;  w += NBMAX * 4;     // zeroed together
    int* gcur_c = (int*)w;  w += NBMAX * 4;
    float* hconst = (float*)w; w += 68 * 4;
    w = (char*)(((uintptr_t)w + 255) & ~(uintptr_t)255);
    unsigned int* P_p = (unsigned int*)w;  w += (size_t)nbP * CAP * 4;
    unsigned int* P_c = (unsigned int*)w;  w += (size_t)nbC * CAP * 4;
    int* ss_p = (int*)w;    w += (size_t)nbP * CAP * 4;
    int* ro_p = (int*)w;    w += (size_t)NP * 4;
    int* dg_p = (int*)w;    w += (size_t)NP * 4;
    w = (char*)(((uintptr_t)w + 255) & ~(uintptr_t)255);
    _Float16* y_c = (_Float16*)w; w += (size_t)NC * 32 * 2;
    _Float16* y_p = (_Float16*)w; w += (size_t)NP * 32 * 2;
    _Float16* s_p = (_Float16*)w; w += (size_t)NP * 32 * 2;  // xp @ W1r_r1
    _Float16* s_c = (_Float16*)w; w += (size_t)NC * 32 * 2;  // xc @ W1r_r2
    w = (char*)(((uintptr_t)w + 255) & ~(uintptr_t)255);
    float* t_c = (float*)w; w += (size_t)NC * 4;
    float* u_p = (float*)w; w += (size_t)NP * 4;

    const int bprB = (E + 8191) / 8192;

    // 1. init: zero cursors (block 0) + head constants (block 1)
    kinit<<<2, 256, 0, stream>>>((int4*)gcur_p, 2 * NBMAX / 4,
                                 W2l_r1, W2r_r1, b2_r1, Wlin, blin, hconst);

    // 2. bucket binning (frozen)
    kbin<<<2 * bprB, 512, 0, stream>>>(e_c2p, e_p2c, E, gcur_p, gcur_c, P_p, P_c, bprB);

    // 3. MFMA fused projections (refcheck-proven, ~28us est.)
    const int tblocksC = (NC + 63) / 64;
    const int tblocksP = (NP + 63) / 64;
    proj_mfma<<<tblocksC + tblocksP, 256, 0, stream>>>(
        xc, W1l_r1, W1r_r2, y_c, s_c, NC, tblocksC,
        xp, W1l_r2, W1r_r1, y_p, s_p, NP);

    // 4. fused per-bucket sort + layer-1 pull (R8 byte-exact)
    const int nbMax = (nbP > nbC) ? nbP : nbC;
    const int spBlocks = 8 * ((nbMax + 3) / 4);
    sortpull<<<spBlocks, 512, 0, stream>>>(
        P_p, gcur_p, y_c, s_p, b1_r1, u_p, NP, nbP,
        P_c, gcur_c, y_p, s_c, b1_r2, t_c, NC, nbC,
        hconst, ss_p, ro_p, dg_p);

    // 5. layer-2 scalar pull + sigmoid (4B gathers from 400KB table)
    pull_l2_scalar<<<(NP * 4 + 255) / 256, 256, 0, stream>>>(
        ro_p, dg_p, ss_p, t_c, u_p, hconst, out, NP);
}